// Round 8
// baseline (217.851 us; speedup 1.0000x reference)
//
#include <hip/hip_runtime.h>
#include <hip/hip_bf16.h>

#define BS  4
#define SEQ 4096
#define DK  128

// p = exp(s_raw / sqrt(128)) = exp2(C1_SCALE * s_raw)
#define C1_SCALE (1.4426950408889634f / 11.313708498984761f)

typedef __attribute__((ext_vector_type(8))) short bf16x8;
typedef __attribute__((ext_vector_type(4))) float f32x4;
typedef unsigned short ushort_t;

__device__ inline unsigned pk_bf16(float a, float b) {
    __hip_bfloat162 h = __float22bfloat162_rn(make_float2(a, b));
    union { __hip_bfloat162 h2; unsigned u; } cv;
    cv.h2 = h;
    return cv.u;
}

__device__ inline bf16x8 pk8(float4 a, float4 b) {
    union { bf16x8 v; unsigned u[4]; } r;
    r.u[0] = pk_bf16(a.x, a.y);
    r.u[1] = pk_bf16(a.z, a.w);
    r.u[2] = pk_bf16(b.x, b.y);
    r.u[3] = pk_bf16(b.z, b.w);
    return r.v;
}

// async global->LDS, 16B per lane; lds base must be wave-uniform
__device__ inline void gld_lds16(const ushort_t* g, ushort_t* l) {
    __builtin_amdgcn_global_load_lds(
        (const __attribute__((address_space(1))) unsigned int*)g,
        (__attribute__((address_space(3))) unsigned int*)l,
        16, 0, 0);
}

// ---------------------------------------------------------------------------
// Plain bf16 casts of Q and K (row-major). 8 elems/thread each.
// ---------------------------------------------------------------------------
__global__ __launch_bounds__(256) void cast_qk(
    const float* __restrict__ Q, const float* __restrict__ K,
    ushort_t* __restrict__ Qb, ushort_t* __restrict__ Kb)
{
    size_t i = ((size_t)blockIdx.x * 256 + threadIdx.x) * 8;
    float4 a = *(const float4*)(Q + i), b = *(const float4*)(Q + i + 4);
    *(bf16x8*)(Qb + i) = pk8(a, b);
    a = *(const float4*)(K + i); b = *(const float4*)(K + i + 4);
    *(bf16x8*)(Kb + i) = pk8(a, b);
}

// ---------------------------------------------------------------------------
// Pass A: P[b,q,k] = exp2(C1 * Q[q].K[k])  (bf16) + column-sum partials.
// grid (kt=32, qs=8, b=4) = 1024 blocks, 256 thr, 16 KB LDS.
// P global layout: [b][qtile=q/64][ktile=k/64][4096] where the 4096-ushort
// tile is the swizzled LDS image passB DMAs: atom16(ql, a=kl/8) at
// ql*8 + (a ^ (ql&7)) atoms.
// C-frags are ds_written into a 2-tile LDS image; every 2 iters the block
// flushes 16 KB with fully-coalesced global_store_dwordx4 (R7 scattered
// 16B granules from registers -> store-retire bound at 92 us).
// ---------------------------------------------------------------------------
__global__ __launch_bounds__(256) void sdpa_passA(
    const ushort_t* __restrict__ Qb, const ushort_t* __restrict__ Kb,
    ushort_t* __restrict__ Pg, float* __restrict__ lp)
{
    __shared__ ushort_t Ps[8192];   // 2 units (k-tiles) x 4096

    const int kt = blockIdx.x, qs = blockIdx.y, b = blockIdx.z;
    const int tid = threadIdx.x;
    const int w = tid >> 6, lane = tid & 63, ln = lane & 15, quad = lane >> 4;

    bf16x8 ka[2][4];   // A-frags: k rows kt*128 + w*32 + mt*16 + ln
#pragma unroll
    for (int mt = 0; mt < 2; ++mt)
#pragma unroll
        for (int c = 0; c < 4; ++c)
            ka[mt][c] = *(const bf16x8*)(Kb +
                ((size_t)(b * SEQ) + kt * 128 + w * 32 + mt * 16 + ln) * DK +
                c * 32 + quad * 8);

    float ls[2][4] = {};
    const ushort_t* qbase = Qb + ((size_t)(b * SEQ) + qs * 512 + ln) * DK + quad * 8;

    bf16x8 qf0[2][4], qf1[2][4];

#define A_PRE(QF, IT)                                                          \
    {                                                                          \
        _Pragma("unroll")                                                      \
        for (int nt = 0; nt < 2; ++nt)                                         \
            _Pragma("unroll")                                                  \
            for (int c = 0; c < 4; ++c)                                        \
                QF[nt][c] = *(const bf16x8*)(qbase +                           \
                    ((size_t)((IT) * 32 + nt * 16)) * DK + c * 32);            \
    }

#define A_CMP(QF, IT)                                                          \
    {                                                                          \
        _Pragma("unroll")                                                      \
        for (int mt = 0; mt < 2; ++mt)                                         \
            _Pragma("unroll")                                                  \
            for (int nt = 0; nt < 2; ++nt) {                                   \
                f32x4 s = {0.f, 0.f, 0.f, 0.f};                                \
                _Pragma("unroll")                                              \
                for (int c = 0; c < 4; ++c)                                    \
                    s = __builtin_amdgcn_mfma_f32_16x16x32_bf16(               \
                        ka[mt][c], QF[nt][c], s, 0, 0, 0);                     \
                float e0 = __builtin_amdgcn_exp2f(C1_SCALE * s[0]);            \
                float e1 = __builtin_amdgcn_exp2f(C1_SCALE * s[1]);            \
                float e2 = __builtin_amdgcn_exp2f(C1_SCALE * s[2]);            \
                float e3 = __builtin_amdgcn_exp2f(C1_SCALE * s[3]);            \
                ls[mt][0] += e0; ls[mt][1] += e1;                              \
                ls[mt][2] += e2; ls[mt][3] += e3;                              \
                uint2 pw; pw.x = pk_bf16(e0, e1); pw.y = pk_bf16(e2, e3);      \
                const int ql = (((IT) & 1) * 32) + nt * 16 + ln;               \
                const int aa = (w & 1) * 4 + mt * 2 + (quad >> 1);             \
                *(uint2*)&Ps[(w >> 1) * 4096 +                                 \
                             (ql * 8 + (aa ^ (ql & 7))) * 8 + (quad & 1) * 4] = pw; \
            }                                                                  \
    }

    A_PRE(qf0, 0)
    for (int ii = 0; ii < 8; ++ii) {
        const int i0 = 2 * ii;
        A_PRE(qf1, i0 + 1)
        A_CMP(qf0, i0)
        if (ii < 7) A_PRE(qf0, i0 + 2)
        A_CMP(qf1, i0 + 1)
        __syncthreads();   // all ds_writes of this 64q x 128k group done
        {
            // flush 16 KB: qtile = qs*8 + ii, ktiles kt*2 .. kt*2+1 contiguous
            const size_t gb = (((size_t)(b * 64 + qs * 8 + ii)) * 64 + kt * 2) * 4096;
#pragma unroll
            for (int j = 0; j < 4; ++j) {
                uint4 t4 = *(const uint4*)&Ps[(j * 256 + tid) * 8];
                *(uint4*)(Pg + gb + (size_t)(j * 256 + tid) * 8) = t4;
            }
        }
        __syncthreads();   // flush reads done; Ps reusable
    }
#undef A_PRE
#undef A_CMP

#pragma unroll
    for (int mt = 0; mt < 2; ++mt)
#pragma unroll
        for (int r = 0; r < 4; ++r) {
            float vv = ls[mt][r];
            vv += __shfl_xor(vv, 1);
            vv += __shfl_xor(vv, 2);
            vv += __shfl_xor(vv, 4);
            vv += __shfl_xor(vv, 8);
            ls[mt][r] = vv;
        }
    if (ln < 8) {
        int k = kt * 128 + w * 32 + (ln >> 2) * 16 + quad * 4 + (ln & 3);
        lp[((size_t)(qs * BS + b)) * SEQ + k] = ls[ln >> 2][ln & 3];
    }
}

// ---------------------------------------------------------------------------
// VbT[b][d][k] = bf16( V[b][k][d] / l[b][k] ), l = sum of 8 qs-partials.
// ---------------------------------------------------------------------------
__global__ __launch_bounds__(256) void vb_transpose(
    const float* __restrict__ V, const float* __restrict__ lp,
    ushort_t* __restrict__ VbT)
{
    __shared__ float Vl[64][132];
    __shared__ float Wl[64];

    const int kt = blockIdx.x, b = blockIdx.y;
    const int tid = threadIdx.x;
    const int k0 = kt * 64;
    {
        int r = tid >> 2, sg = tid & 3;
        const float* src = V + ((size_t)(b * SEQ) + k0 + r) * DK + sg * 32;
#pragma unroll
        for (int i = 0; i < 8; ++i)
            *(float4*)&Vl[r][sg * 32 + i * 4] = *(const float4*)(src + i * 4);
    }
    if (tid < 64) {
        float s = 0.f;
#pragma unroll
        for (int qs = 0; qs < 8; ++qs)
            s += lp[((size_t)(qs * BS + b)) * SEQ + k0 + tid];
        Wl[tid] = 1.0f / s;
    }
    __syncthreads();

    const int d = tid >> 1, kh = tid & 1;
    unsigned u[16];
#pragma unroll
    for (int j = 0; j < 16; ++j) {
        int row = kh * 32 + j * 2;
        u[j] = pk_bf16(Vl[row][d] * Wl[row], Vl[row + 1][d] * Wl[row + 1]);
    }
    ushort_t* dst = VbT + ((size_t)(b * DK) + d) * SEQ + k0 + kh * 32;
#pragma unroll
    for (int i = 0; i < 4; ++i) {
        uint4 t4; t4.x = u[i*4]; t4.y = u[i*4+1]; t4.z = u[i*4+2]; t4.w = u[i*4+3];
        *(uint4*)(dst + i * 8) = t4;
    }
}

// ---------------------------------------------------------------------------
// Pass B: O[b,q,:] += P[q,:] . V'[:,d]   — pure streaming GEMM.
// grid (x=16 (ks,b) [XCD-pinned], y=64 qt), 256 thr, 16 KB LDS.
// ONE barrier per phase: DMA(i+1) targets the Pt buffer whose readers all
// finished before barrier(i); vmcnt(0) at barrier(i+1) drains it.
// ---------------------------------------------------------------------------
__global__ __launch_bounds__(256) void sdpa_passB(
    const ushort_t* __restrict__ Pg, const ushort_t* __restrict__ VbT,
    float* __restrict__ O)
{
    __shared__ ushort_t Pt[2][4096];

    const int g  = blockIdx.x;          // ks*4 + b
    const int qt = blockIdx.y;
    const int ks = g >> 2, b = g & 3;
    const int tid = threadIdx.x;
    const int w = tid >> 6, lane = tid & 63, ln = lane & 15, quad = lane >> 4;

    f32x4 acc[4][2];
#pragma unroll
    for (int i = 0; i < 4; ++i)
#pragma unroll
        for (int j = 0; j < 2; ++j) acc[i][j] = (f32x4){0.f, 0.f, 0.f, 0.f};

    const ushort_t* ptile = Pg + (((size_t)(b * 64 + qt)) * 64 + ks * 16) * 4096;
    const ushort_t* vfp = VbT + ((size_t)(b * DK) + w * 32 + ln) * SEQ + ks * 1024 + quad * 8;

    bf16x8 vf0[4], vf1[4];

#define B_DMA(BUF, I)                                                          \
    {                                                                          \
        const ushort_t* src = ptile + (size_t)(I) * 4096;                      \
        _Pragma("unroll")                                                      \
        for (int j = 0; j < 2; ++j)                                            \
            gld_lds16(src + (j * 256 + tid) * 8,                               \
                      &Pt[BUF][(j * 256 + w * 64) * 8]);                       \
    }

#define B_PRV(VF, I)                                                           \
    {                                                                          \
        _Pragma("unroll")                                                      \
        for (int dt = 0; dt < 2; ++dt)                                         \
            _Pragma("unroll")                                                  \
            for (int kc = 0; kc < 2; ++kc)                                     \
                VF[kc * 2 + dt] = *(const bf16x8*)(vfp +                       \
                    (size_t)dt * 16 * SEQ + (I) * 64 + kc * 32);               \
    }

#define B_PV(BUF, VF)                                                          \
    {                                                                          \
        _Pragma("unroll")                                                      \
        for (int kc = 0; kc < 2; ++kc) {                                       \
            bf16x8 pa[4];                                                      \
            _Pragma("unroll")                                                  \
            for (int qf2 = 0; qf2 < 4; ++qf2)                                  \
                pa[qf2] = *(const bf16x8*)&Pt[BUF][(qf2 * 16 + ln) * 64 +      \
                                    (((kc * 4 + quad) ^ (ln & 7)) * 8)];       \
            _Pragma("unroll")                                                  \
            for (int qf2 = 0; qf2 < 4; ++qf2)                                  \
                _Pragma("unroll")                                              \
                for (int dt = 0; dt < 2; ++dt)                                 \
                    acc[qf2][dt] = __builtin_amdgcn_mfma_f32_16x16x32_bf16(    \
                        pa[qf2], VF[kc * 2 + dt], acc[qf2][dt], 0, 0, 0);      \
        }                                                                      \
    }

    B_DMA(0, 0)
    B_PRV(vf0, 0)
    for (int ii = 0; ii < 8; ++ii) {
        const int i0 = 2 * ii;
        // phase i0: Pt[0] ready after barrier; DMA next into Pt[1]
        __syncthreads();
        B_DMA(1, i0 + 1)
        B_PRV(vf1, i0 + 1)
        B_PV(0, vf0)
        // phase i0+1: Pt[1] ready after barrier; DMA next into Pt[0]
        __syncthreads();
        if (ii < 7) {
            B_DMA(0, i0 + 2)
            B_PRV(vf0, i0 + 2)
        }
        B_PV(1, vf1)
    }
#undef B_DMA
#undef B_PRV
#undef B_PV

#pragma unroll
    for (int qf2 = 0; qf2 < 4; ++qf2)
#pragma unroll
        for (int dt = 0; dt < 2; ++dt)
#pragma unroll
            for (int r = 0; r < 4; ++r)
                atomicAdd(&O[((size_t)(b * SEQ) + qt * 64 + qf2 * 16 + quad * 4 + r) * DK +
                             w * 32 + dt * 16 + ln], acc[qf2][dt][r]);
}

// ===========================================================================
// Fallback path (R6 kernels) — used only if ws_size can't hold P (134 MB).
// ===========================================================================
__global__ __launch_bounds__(256) void sdpa_lsum_fb(
    const ushort_t* __restrict__ Qb, const ushort_t* __restrict__ Kb,
    float* __restrict__ lp)
{
    const int kt = blockIdx.x, qs = blockIdx.y, b = blockIdx.z;
    const int tid = threadIdx.x;
    const int w = tid >> 6, lane = tid & 63, ln = lane & 15, quad = lane >> 4;

    bf16x8 ka[2][4];
#pragma unroll
    for (int mt = 0; mt < 2; ++mt)
#pragma unroll
        for (int c = 0; c < 4; ++c)
            ka[mt][c] = *(const bf16x8*)(Kb +
                ((size_t)(b * SEQ) + kt * 128 + w * 32 + mt * 16 + ln) * DK +
                c * 32 + quad * 8);

    float ls[2][4] = {};
    const ushort_t* qbase = Qb + ((size_t)(b * SEQ) + qs * 512 + ln) * DK + quad * 8;
    bf16x8 qf0[2][4], qf1[2][4];

#define L_PRE(QF, IT)                                                          \
    {                                                                          \
        _Pragma("unroll")                                                      \
        for (int nt = 0; nt < 2; ++nt)                                         \
            _Pragma("unroll")                                                  \
            for (int c = 0; c < 4; ++c)                                        \
                QF[nt][c] = *(const bf16x8*)(qbase +                           \
                    ((size_t)((IT) * 32 + nt * 16)) * DK + c * 32);            \
    }
#define L_CMP(QF)                                                              \
    {                                                                          \
        _Pragma("unroll")                                                      \
        for (int mt = 0; mt < 2; ++mt)                                         \
            _Pragma("unroll")                                                  \
            for (int nt = 0; nt < 2; ++nt) {                                   \
                f32x4 s = {0.f, 0.f, 0.f, 0.f};                                \
                _Pragma("unroll")                                              \
                for (int c = 0; c < 4; ++c)                                    \
                    s = __builtin_amdgcn_mfma_f32_16x16x32_bf16(               \
                        ka[mt][c], QF[nt][c], s, 0, 0, 0);                     \
                _Pragma("unroll")                                              \
                for (int r = 0; r < 4; ++r)                                    \
                    ls[mt][r] += __builtin_amdgcn_exp2f(C1_SCALE * s[r]);      \
            }                                                                  \
    }
    L_PRE(qf0, 0)
    for (int ii = 0; ii < 8; ++ii) {
        const int i0 = 2 * ii;
        L_PRE(qf1, i0 + 1)
        L_CMP(qf0)
        if (ii < 7) L_PRE(qf0, i0 + 2)
        L_CMP(qf1)
    }
#undef L_PRE
#undef L_CMP

#pragma unroll
    for (int mt = 0; mt < 2; ++mt)
#pragma unroll
        for (int r = 0; r < 4; ++r) {
            float vv = ls[mt][r];
            vv += __shfl_xor(vv, 1);
            vv += __shfl_xor(vv, 2);
            vv += __shfl_xor(vv, 4);
            vv += __shfl_xor(vv, 8);
            ls[mt][r] = vv;
        }
    if (ln < 8) {
        int k = kt * 128 + w * 32 + (ln >> 2) * 16 + quad * 4 + (ln & 3);
        lp[((size_t)(qs * BS + b)) * SEQ + k] = ls[ln >> 2][ln & 3];
    }
}

__global__ __launch_bounds__(256) void sdpa_out_fb(
    const ushort_t* __restrict__ Qb, const ushort_t* __restrict__ Kb,
    const ushort_t* __restrict__ VbT, float* __restrict__ O)
{
    __shared__ ushort_t Pt[2][64 * 64];

    const int g  = blockIdx.x;
    const int qt = blockIdx.y;
    const int ks = g >> 2, b = g & 3;
    const int tid = threadIdx.x;
    const int w = tid >> 6, lane = tid & 63, ln = lane & 15, quad = lane >> 4;

    bf16x8 qa[4][4];
#pragma unroll
    for (int nt = 0; nt < 4; ++nt)
#pragma unroll
        for (int c = 0; c < 4; ++c)
            qa[c][nt] = *(const bf16x8*)(Qb +
                ((size_t)(b * SEQ) + qt * 64 + nt * 16 + ln) * DK + c * 32 + quad * 8);

    f32x4 acc[4][2];
#pragma unroll
    for (int i = 0; i < 4; ++i)
#pragma unroll
        for (int j = 0; j < 2; ++j) acc[i][j] = (f32x4){0.f, 0.f, 0.f, 0.f};

    const ushort_t* kfp = Kb + ((size_t)(b * SEQ) + ks * 1024 + w * 16 + ln) * DK + quad * 8;
    const ushort_t* vfp = VbT + ((size_t)(b * DK) + w * 32 + ln) * SEQ + ks * 1024 + quad * 8;

    bf16x8 kf0[4], kf1[4], vf0[4], vf1[4];

#define QK_PHASE(P, KF)                                                        \
    {                                                                          \
        _Pragma("unroll")                                                      \
        for (int nt = 0; nt < 4; ++nt) {                                       \
            f32x4 s = {0.f, 0.f, 0.f, 0.f};                                    \
            _Pragma("unroll")                                                  \
            for (int c = 0; c < 4; ++c)                                        \
                s = __builtin_amdgcn_mfma_f32_16x16x32_bf16(KF[c], qa[c][nt], s, 0, 0, 0); \
            uint2 pw;                                                          \
            pw.x = pk_bf16(__builtin_amdgcn_exp2f(C1_SCALE * s[0]),            \
                           __builtin_amdgcn_exp2f(C1_SCALE * s[1]));           \
            pw.y = pk_bf16(__builtin_amdgcn_exp2f(C1_SCALE * s[2]),            \
                           __builtin_amdgcn_exp2f(C1_SCALE * s[3]));           \
            const int q = nt * 16 + ln;                                        \
            const int a16 = w * 2 + (quad >> 1);                               \
            *(uint2*)&Pt[P][q * 64 + ((a16 ^ (q & 7)) * 8) + (quad & 1) * 4] = pw; \
        }                                                                      \
    }
#define PREFETCH(KF, VF, I1)                                                   \
    {                                                                          \
        _Pragma("unroll")                                                      \
        for (int c = 0; c < 4; ++c)                                            \
            KF[c] = *(const bf16x8*)(kfp + (size_t)(I1) * 64 * DK + c * 32);   \
        _Pragma("unroll")                                                      \
        for (int dt = 0; dt < 2; ++dt)                                         \
            _Pragma("unroll")                                                  \
            for (int kc = 0; kc < 2; ++kc)                                     \
                VF[kc * 2 + dt] = *(const bf16x8*)(vfp +                       \
                    (size_t)dt * 16 * SEQ + (size_t)(I1) * 64 + kc * 32);      \
    }
#define PV_PHASE(P, VF)                                                        \
    {                                                                          \
        _Pragma("unroll")                                                      \
        for (int kc = 0; kc < 2; ++kc) {                                       \
            bf16x8 pa[4];                                                      \
            _Pragma("unroll")                                                  \
            for (int qf2 = 0; qf2 < 4; ++qf2)                                  \
                pa[qf2] = *(const bf16x8*)&Pt[P][(qf2 * 16 + ln) * 64 +        \
                                    (((kc * 4 + quad) ^ (ln & 7)) * 8)];       \
            _Pragma("unroll")                                                  \
            for (int qf2 = 0; qf2 < 4; ++qf2)                                  \
                _Pragma("unroll")                                              \
                for (int dt = 0; dt < 2; ++dt)                                 \
                    acc[qf2][dt] = __builtin_amdgcn_mfma_f32_16x16x32_bf16(    \
                        pa[qf2], VF[kc * 2 + dt], acc[qf2][dt], 0, 0, 0);      \
        }                                                                      \
    }

#pragma unroll
    for (int c = 0; c < 4; ++c)
        kf0[c] = *(const bf16x8*)(kfp + c * 32);
#pragma unroll
    for (int dt = 0; dt < 2; ++dt)
#pragma unroll
        for (int kc = 0; kc < 2; ++kc)
            vf0[kc * 2 + dt] = *(const bf16x8*)(vfp + (size_t)dt * 16 * SEQ + kc * 32);

    for (int ii = 0; ii < 8; ++ii) {
        const int i0 = 2 * ii;
        PREFETCH(kf1, vf1, i0 + 1)
        QK_PHASE(0, kf0)
        __syncthreads();
        PV_PHASE(0, vf0)
        if (ii < 7) PREFETCH(kf0, vf0, i0 + 2)
        QK_PHASE(1, kf1)
        __syncthreads();
        PV_PHASE(1, vf1)
    }
#undef QK_PHASE
#undef PREFETCH
#undef PV_PHASE

#pragma unroll
    for (int qf2 = 0; qf2 < 4; ++qf2)
#pragma unroll
        for (int dt = 0; dt < 2; ++dt)
#pragma unroll
            for (int r = 0; r < 4; ++r)
                atomicAdd(&O[((size_t)(b * SEQ) + qt * 64 + qf2 * 16 + quad * 4 + r) * DK +
                             w * 32 + dt * 16 + ln], acc[qf2][dt][r]);
}

extern "C" void kernel_launch(void* const* d_in, const int* in_sizes, int n_in,
                              void* d_out, int out_size, void* d_ws, size_t ws_size,
                              hipStream_t stream) {
    const float* q = (const float*)d_in[0];
    const float* k = (const float*)d_in[1];
    const float* v = (const float*)d_in[2];
    float* out = (float*)d_out;

    float*    lp  = (float*)d_ws;                                   // 512 KB used
    ushort_t* Qb  = (ushort_t*)((char*)d_ws + (1 << 20));           // 4 MB
    ushort_t* Kb  = Qb + (size_t)BS * SEQ * DK;                     // 4 MB
    ushort_t* VbT = Kb + (size_t)BS * SEQ * DK;                     // 4 MB
    ushort_t* Pg  = VbT + (size_t)BS * SEQ * DK;                    // 134 MB

    const size_t need = (1u << 20) + 3 * (size_t)BS * SEQ * DK * 2 +
                        (size_t)BS * SEQ * SEQ * 2;

    hipMemsetAsync(out, 0, (size_t)BS * SEQ * DK * sizeof(float), stream);
    cast_qk<<<dim3(BS * SEQ * DK / 8 / 256), 256, 0, stream>>>(q, k, Qb, Kb);

    if (ws_size >= need) {
        sdpa_passA  <<<dim3(32, 8, 4), 256, 0, stream>>>(Qb, Kb, Pg, lp);
        vb_transpose<<<dim3(64, 4),    256, 0, stream>>>(v, lp, VbT);
        sdpa_passB  <<<dim3(16, 64),   256, 0, stream>>>(Pg, VbT, out);
    } else {
        sdpa_lsum_fb<<<dim3(32, 8, 4), 256, 0, stream>>>(Qb, Kb, lp);
        vb_transpose<<<dim3(64, 4),    256, 0, stream>>>(v, lp, VbT);
        sdpa_out_fb <<<dim3(16, 64),   256, 0, stream>>>(Qb, Kb, VbT, out);
    }
}

// Round 9
// 171.488 us; speedup vs baseline: 1.2704x; 1.2704x over previous
//
#include <hip/hip_runtime.h>
#include <hip/hip_bf16.h>

#define BS  4
#define SEQ 4096
#define DK  128

// p = exp(s_raw / sqrt(128)) = exp2(C1_SCALE * s_raw)
#define C1_SCALE (1.4426950408889634f / 11.313708498984761f)

typedef __attribute__((ext_vector_type(8))) short bf16x8;
typedef __attribute__((ext_vector_type(4))) float f32x4;
typedef unsigned short ushort_t;

__device__ inline unsigned pk_bf16(float a, float b) {
    __hip_bfloat162 h = __float22bfloat162_rn(make_float2(a, b));
    union { __hip_bfloat162 h2; unsigned u; } cv;
    cv.h2 = h;
    return cv.u;
}

__device__ inline bf16x8 pk8(float4 a, float4 b) {
    union { bf16x8 v; unsigned u[4]; } r;
    r.u[0] = pk_bf16(a.x, a.y);
    r.u[1] = pk_bf16(a.z, a.w);
    r.u[2] = pk_bf16(b.x, b.y);
    r.u[3] = pk_bf16(b.z, b.w);
    return r.v;
}

// async global->LDS, 16B per lane; lds base must be wave-uniform
__device__ inline void gld_lds16(const ushort_t* g, ushort_t* l) {
    __builtin_amdgcn_global_load_lds(
        (const __attribute__((address_space(1))) unsigned int*)g,
        (__attribute__((address_space(3))) unsigned int*)l,
        16, 0, 0);
}

// ---------------------------------------------------------------------------
// Swizzled-row bf16 cast of Q and K (R3 layout): row r (256 B = 16 atoms of
// 16 B), atom a stored at position a ^ (r & 15). Linear DMA of 16-row-aligned
// tiles reproduces the swizzled LDS image; fragment reads use atom
// ((c*4+quad) ^ ln) -> <=2-way LDS banking.
// ---------------------------------------------------------------------------
__global__ __launch_bounds__(256) void cast_qk_sw(
    const float* __restrict__ Q, const float* __restrict__ K,
    ushort_t* __restrict__ Qb, ushort_t* __restrict__ Kb)
{
    const int g = blockIdx.x * 256 + threadIdx.x;   // atom id
    const int q = g >> 4, ap = g & 15;
    const int a = ap ^ (q & 15);
    const float* src = Q + (size_t)q * DK + a * 8;
    float4 x = *(const float4*)src, y = *(const float4*)(src + 4);
    *(bf16x8*)(Qb + (size_t)g * 8) = pk8(x, y);
    src = K + (size_t)q * DK + a * 8;
    x = *(const float4*)src; y = *(const float4*)(src + 4);
    *(bf16x8*)(Kb + (size_t)g * 8) = pk8(x, y);
}

// ---------------------------------------------------------------------------
// Pass A (m97 recipe): P tiles + column-sum partials.
// grid (kt=32, qs=8, b=4) = 1024 blocks, 256 thr, 32 KB LDS.
// K rows stationary in regs (A-operand); Q streamed global->LDS via
// global_load_lds, double-buffered; P bounced through LDS, flushed coalesced.
// 3 barriers per 2 iters; per wave per iter: 16 MFMA, 8 ds_read_b128.
// ---------------------------------------------------------------------------
__global__ __launch_bounds__(256) void sdpa_passA(
    const ushort_t* __restrict__ Qb, const ushort_t* __restrict__ Kb,
    ushort_t* __restrict__ Pg, float* __restrict__ lp)
{
    __shared__ ushort_t Qs[2][4096];   // 2 x (32 q x 128 dk), swizzled rows
    __shared__ ushort_t Ps[8192];      // 2 k-tiles x 4096 (passB tile image)

    const int kt = blockIdx.x, qs = blockIdx.y, b = blockIdx.z;
    const int tid = threadIdx.x;
    const int w = tid >> 6, lane = tid & 63, ln = lane & 15, quad = lane >> 4;

    bf16x8 ka[2][4];   // A-frags: k rows kt*128 + w*32 + mt*16 + ln (swizzled)
#pragma unroll
    for (int mt = 0; mt < 2; ++mt)
#pragma unroll
        for (int c = 0; c < 4; ++c)
            ka[mt][c] = *(const bf16x8*)(Kb +
                ((size_t)(b * SEQ) + kt * 128 + w * 32 + mt * 16 + ln) * DK +
                (((c * 4 + quad) ^ ln) * 8));

    float ls[2][4] = {};
    const ushort_t* qtb = Qb + ((size_t)(b * SEQ + qs * 512)) * DK;

#define A_DMA(BUF, I)                                                          \
    {                                                                          \
        _Pragma("unroll")                                                      \
        for (int j = 0; j < 2; ++j)                                            \
            gld_lds16(qtb + (size_t)(I) * 4096 + (j * 256 + tid) * 8,          \
                      &Qs[BUF][(j * 256 + w * 64) * 8]);                       \
    }

#define A_CMP(BUF, IT)                                                         \
    {                                                                          \
        bf16x8 qf[2][4];                                                       \
        _Pragma("unroll")                                                      \
        for (int nt = 0; nt < 2; ++nt)                                         \
            _Pragma("unroll")                                                  \
            for (int c = 0; c < 4; ++c)                                        \
                qf[nt][c] = *(const bf16x8*)&Qs[BUF][(nt * 16 + ln) * 128 +    \
                                    (((c * 4 + quad) ^ ln) * 8)];              \
        _Pragma("unroll")                                                      \
        for (int mt = 0; mt < 2; ++mt)                                         \
            _Pragma("unroll")                                                  \
            for (int nt = 0; nt < 2; ++nt) {                                   \
                f32x4 s = {0.f, 0.f, 0.f, 0.f};                                \
                _Pragma("unroll")                                              \
                for (int c = 0; c < 4; ++c)                                    \
                    s = __builtin_amdgcn_mfma_f32_16x16x32_bf16(               \
                        ka[mt][c], qf[nt][c], s, 0, 0, 0);                     \
                float e0 = __builtin_amdgcn_exp2f(C1_SCALE * s[0]);            \
                float e1 = __builtin_amdgcn_exp2f(C1_SCALE * s[1]);            \
                float e2 = __builtin_amdgcn_exp2f(C1_SCALE * s[2]);            \
                float e3 = __builtin_amdgcn_exp2f(C1_SCALE * s[3]);            \
                ls[mt][0] += e0; ls[mt][1] += e1;                              \
                ls[mt][2] += e2; ls[mt][3] += e3;                              \
                uint2 pw; pw.x = pk_bf16(e0, e1); pw.y = pk_bf16(e2, e3);      \
                const int ql = (((IT) & 1) * 32) + nt * 16 + ln;               \
                const int aa = (w & 1) * 4 + mt * 2 + (quad >> 1);             \
                *(uint2*)&Ps[(w >> 1) * 4096 +                                 \
                             (ql * 8 + (aa ^ (ql & 7))) * 8 + (quad & 1) * 4] = pw; \
            }                                                                  \
    }

    A_DMA(0, 0)
    for (int ii = 0; ii < 8; ++ii) {
        const int i0 = 2 * ii;
        __syncthreads();              // Qs[0]=tile i0 ready; Ps flush done
        A_DMA(1, i0 + 1)
        A_CMP(0, i0)
        __syncthreads();              // Qs[1]=tile i0+1 ready; Qs[0] readers done
        if (ii < 7) A_DMA(0, i0 + 2)
        A_CMP(1, i0 + 1)
        __syncthreads();              // all Ps ds_writes visible
        {   // flush 16 KB coalesced: qtile qs*8+ii, ktiles kt*2..kt*2+1
            const size_t gb = (((size_t)(b * 64 + qs * 8 + ii)) * 64 + kt * 2) * 4096;
#pragma unroll
            for (int j = 0; j < 4; ++j) {
                uint4 t4 = *(const uint4*)&Ps[(j * 256 + tid) * 8];
                *(uint4*)(Pg + gb + (size_t)(j * 256 + tid) * 8) = t4;
            }
        }
    }
#undef A_DMA
#undef A_CMP

#pragma unroll
    for (int mt = 0; mt < 2; ++mt)
#pragma unroll
        for (int r = 0; r < 4; ++r) {
            float vv = ls[mt][r];
            vv += __shfl_xor(vv, 1);
            vv += __shfl_xor(vv, 2);
            vv += __shfl_xor(vv, 4);
            vv += __shfl_xor(vv, 8);
            ls[mt][r] = vv;
        }
    if (ln < 8) {
        int k = kt * 128 + w * 32 + (ln >> 2) * 16 + quad * 4 + (ln & 3);
        lp[((size_t)(qs * BS + b)) * SEQ + k] = ls[ln >> 2][ln & 3];
    }
}

// ---------------------------------------------------------------------------
// VbT[b][d][k] = bf16( V[b][k][d] / l[b][k] ), l = sum of 8 qs-partials.
// ---------------------------------------------------------------------------
__global__ __launch_bounds__(256) void vb_transpose(
    const float* __restrict__ V, const float* __restrict__ lp,
    ushort_t* __restrict__ VbT)
{
    __shared__ float Vl[64][132];
    __shared__ float Wl[64];

    const int kt = blockIdx.x, b = blockIdx.y;
    const int tid = threadIdx.x;
    const int k0 = kt * 64;
    {
        int r = tid >> 2, sg = tid & 3;
        const float* src = V + ((size_t)(b * SEQ) + k0 + r) * DK + sg * 32;
#pragma unroll
        for (int i = 0; i < 8; ++i)
            *(float4*)&Vl[r][sg * 32 + i * 4] = *(const float4*)(src + i * 4);
    }
    if (tid < 64) {
        float s = 0.f;
#pragma unroll
        for (int qs = 0; qs < 8; ++qs)
            s += lp[((size_t)(qs * BS + b)) * SEQ + k0 + tid];
        Wl[tid] = 1.0f / s;
    }
    __syncthreads();

    const int d = tid >> 1, kh = tid & 1;
    unsigned u[16];
#pragma unroll
    for (int j = 0; j < 16; ++j) {
        int row = kh * 32 + j * 2;
        u[j] = pk_bf16(Vl[row][d] * Wl[row], Vl[row + 1][d] * Wl[row + 1]);
    }
    ushort_t* dst = VbT + ((size_t)(b * DK) + d) * SEQ + k0 + kh * 32;
#pragma unroll
    for (int i = 0; i < 4; ++i) {
        uint4 t4; t4.x = u[i*4]; t4.y = u[i*4+1]; t4.z = u[i*4+2]; t4.w = u[i*4+3];
        *(uint4*)(dst + i * 8) = t4;
    }
}

// ---------------------------------------------------------------------------
// Pass B: O_partial[ks] = P . V'  — pure streaming GEMM, NO atomics when
// use_partial=1 (plain coalesced stores to Op; reduce4 sums the 4 splits).
// grid (x=16 (ks,b) [XCD-pinned], y=64 qt), 256 thr, 16 KB LDS.
// ---------------------------------------------------------------------------
__global__ __launch_bounds__(256) void sdpa_passB(
    const ushort_t* __restrict__ Pg, const ushort_t* __restrict__ VbT,
    float* __restrict__ Op, float* __restrict__ O, int use_partial)
{
    __shared__ ushort_t Pt[2][4096];

    const int g  = blockIdx.x;          // ks*4 + b
    const int qt = blockIdx.y;
    const int ks = g >> 2, b = g & 3;
    const int tid = threadIdx.x;
    const int w = tid >> 6, lane = tid & 63, ln = lane & 15, quad = lane >> 4;

    f32x4 acc[4][2];
#pragma unroll
    for (int i = 0; i < 4; ++i)
#pragma unroll
        for (int j = 0; j < 2; ++j) acc[i][j] = (f32x4){0.f, 0.f, 0.f, 0.f};

    const ushort_t* ptile = Pg + (((size_t)(b * 64 + qt)) * 64 + ks * 16) * 4096;
    const ushort_t* vfp = VbT + ((size_t)(b * DK) + w * 32 + ln) * SEQ + ks * 1024 + quad * 8;

    bf16x8 vf0[4], vf1[4];

#define B_DMA(BUF, I)                                                          \
    {                                                                          \
        const ushort_t* src = ptile + (size_t)(I) * 4096;                      \
        _Pragma("unroll")                                                      \
        for (int j = 0; j < 2; ++j)                                            \
            gld_lds16(src + (j * 256 + tid) * 8,                               \
                      &Pt[BUF][(j * 256 + w * 64) * 8]);                       \
    }

#define B_PRV(VF, I)                                                           \
    {                                                                          \
        _Pragma("unroll")                                                      \
        for (int dt = 0; dt < 2; ++dt)                                         \
            _Pragma("unroll")                                                  \
            for (int kc = 0; kc < 2; ++kc)                                     \
                VF[kc * 2 + dt] = *(const bf16x8*)(vfp +                       \
                    (size_t)dt * 16 * SEQ + (I) * 64 + kc * 32);               \
    }

#define B_PV(BUF, VF)                                                          \
    {                                                                          \
        _Pragma("unroll")                                                      \
        for (int kc = 0; kc < 2; ++kc) {                                       \
            bf16x8 pa[4];                                                      \
            _Pragma("unroll")                                                  \
            for (int qf2 = 0; qf2 < 4; ++qf2)                                  \
                pa[qf2] = *(const bf16x8*)&Pt[BUF][(qf2 * 16 + ln) * 64 +      \
                                    (((kc * 4 + quad) ^ (ln & 7)) * 8)];       \
            _Pragma("unroll")                                                  \
            for (int qf2 = 0; qf2 < 4; ++qf2)                                  \
                _Pragma("unroll")                                              \
                for (int dt = 0; dt < 2; ++dt)                                 \
                    acc[qf2][dt] = __builtin_amdgcn_mfma_f32_16x16x32_bf16(    \
                        pa[qf2], VF[kc * 2 + dt], acc[qf2][dt], 0, 0, 0);      \
        }                                                                      \
    }

    B_DMA(0, 0)
    B_PRV(vf0, 0)
    for (int ii = 0; ii < 8; ++ii) {
        const int i0 = 2 * ii;
        __syncthreads();
        B_DMA(1, i0 + 1)
        B_PRV(vf1, i0 + 1)
        B_PV(0, vf0)
        __syncthreads();
        if (ii < 7) {
            B_DMA(0, i0 + 2)
            B_PRV(vf0, i0 + 2)
        }
        B_PV(1, vf1)
    }
#undef B_DMA
#undef B_PRV
#undef B_PV

    if (use_partial) {
        float* dst = Op + (size_t)ks * (BS * SEQ * DK) +
                     ((size_t)(b * SEQ) + qt * 64 + quad * 4) * DK + w * 32 + ln;
#pragma unroll
        for (int qf2 = 0; qf2 < 4; ++qf2)
#pragma unroll
            for (int dt = 0; dt < 2; ++dt)
#pragma unroll
                for (int r = 0; r < 4; ++r)
                    dst[((size_t)(qf2 * 16 + r)) * DK + dt * 16] = acc[qf2][dt][r];
    } else {
#pragma unroll
        for (int qf2 = 0; qf2 < 4; ++qf2)
#pragma unroll
            for (int dt = 0; dt < 2; ++dt)
#pragma unroll
                for (int r = 0; r < 4; ++r)
                    atomicAdd(&O[((size_t)(b * SEQ) + qt * 64 + qf2 * 16 + quad * 4 + r) * DK +
                                 w * 32 + dt * 16 + ln], acc[qf2][dt][r]);
    }
}

// ---------------------------------------------------------------------------
// reduce4: O = sum of 4 k-split partials (float4 per thread).
// ---------------------------------------------------------------------------
__global__ __launch_bounds__(256) void reduce4(
    const float* __restrict__ Op, float* __restrict__ O)
{
    const size_t N = (size_t)BS * SEQ * DK;
    size_t i = ((size_t)blockIdx.x * 256 + threadIdx.x) * 4;
    float4 a0 = *(const float4*)(Op + i);
    float4 a1 = *(const float4*)(Op + N + i);
    float4 a2 = *(const float4*)(Op + 2 * N + i);
    float4 a3 = *(const float4*)(Op + 3 * N + i);
    float4 r;
    r.x = a0.x + a1.x + a2.x + a3.x;
    r.y = a0.y + a1.y + a2.y + a3.y;
    r.z = a0.z + a1.z + a2.z + a3.z;
    r.w = a0.w + a1.w + a2.w + a3.w;
    *(float4*)(O + i) = r;
}

// ===========================================================================
// Fallback (no P materialization) — swizzle-adjusted R6 kernels.
// ===========================================================================
__global__ __launch_bounds__(256) void sdpa_lsum_fb(
    const ushort_t* __restrict__ Qb, const ushort_t* __restrict__ Kb,
    float* __restrict__ lp)
{
    const int kt = blockIdx.x, qs = blockIdx.y, b = blockIdx.z;
    const int tid = threadIdx.x;
    const int w = tid >> 6, lane = tid & 63, ln = lane & 15, quad = lane >> 4;

    bf16x8 ka[2][4];
#pragma unroll
    for (int mt = 0; mt < 2; ++mt)
#pragma unroll
        for (int c = 0; c < 4; ++c)
            ka[mt][c] = *(const bf16x8*)(Kb +
                ((size_t)(b * SEQ) + kt * 128 + w * 32 + mt * 16 + ln) * DK +
                (((c * 4 + quad) ^ ln) * 8));

    float ls[2][4] = {};
    const ushort_t* qbase = Qb + ((size_t)(b * SEQ) + qs * 512 + ln) * DK;
    bf16x8 qf0[2][4], qf1[2][4];

#define L_PRE(QF, IT)                                                          \
    {                                                                          \
        _Pragma("unroll")                                                      \
        for (int nt = 0; nt < 2; ++nt)                                         \
            _Pragma("unroll")                                                  \
            for (int c = 0; c < 4; ++c)                                        \
                QF[nt][c] = *(const bf16x8*)(qbase +                           \
                    ((size_t)((IT) * 32 + nt * 16)) * DK +                     \
                    (((c * 4 + quad) ^ ln) * 8));                              \
    }
#define L_CMP(QF)                                                              \
    {                                                                          \
        _Pragma("unroll")                                                      \
        for (int mt = 0; mt < 2; ++mt)                                         \
            _Pragma("unroll")                                                  \
            for (int nt = 0; nt < 2; ++nt) {                                   \
                f32x4 s = {0.f, 0.f, 0.f, 0.f};                                \
                _Pragma("unroll")                                              \
                for (int c = 0; c < 4; ++c)                                    \
                    s = __builtin_amdgcn_mfma_f32_16x16x32_bf16(               \
                        ka[mt][c], QF[nt][c], s, 0, 0, 0);                     \
                _Pragma("unroll")                                              \
                for (int r = 0; r < 4; ++r)                                    \
                    ls[mt][r] += __builtin_amdgcn_exp2f(C1_SCALE * s[r]);      \
            }                                                                  \
    }
    L_PRE(qf0, 0)
    for (int ii = 0; ii < 8; ++ii) {
        const int i0 = 2 * ii;
        L_PRE(qf1, i0 + 1)
        L_CMP(qf0)
        if (ii < 7) L_PRE(qf0, i0 + 2)
        L_CMP(qf1)
    }
#undef L_PRE
#undef L_CMP

#pragma unroll
    for (int mt = 0; mt < 2; ++mt)
#pragma unroll
        for (int r = 0; r < 4; ++r) {
            float vv = ls[mt][r];
            vv += __shfl_xor(vv, 1);
            vv += __shfl_xor(vv, 2);
            vv += __shfl_xor(vv, 4);
            vv += __shfl_xor(vv, 8);
            ls[mt][r] = vv;
        }
    if (ln < 8) {
        int k = kt * 128 + w * 32 + (ln >> 2) * 16 + quad * 4 + (ln & 3);
        lp[((size_t)(qs * BS + b)) * SEQ + k] = ls[ln >> 2][ln & 3];
    }
}

__global__ __launch_bounds__(256) void sdpa_out_fb(
    const ushort_t* __restrict__ Qb, const ushort_t* __restrict__ Kb,
    const ushort_t* __restrict__ VbT, float* __restrict__ O)
{
    __shared__ ushort_t Pt[2][64 * 64];

    const int g  = blockIdx.x;
    const int qt = blockIdx.y;
    const int ks = g >> 2, b = g & 3;
    const int tid = threadIdx.x;
    const int w = tid >> 6, lane = tid & 63, ln = lane & 15, quad = lane >> 4;

    bf16x8 qa[4][4];
#pragma unroll
    for (int nt = 0; nt < 4; ++nt)
#pragma unroll
        for (int c = 0; c < 4; ++c)
            qa[c][nt] = *(const bf16x8*)(Qb +
                ((size_t)(b * SEQ) + qt * 64 + nt * 16 + ln) * DK +
                (((c * 4 + quad) ^ ln) * 8));

    f32x4 acc[4][2];
#pragma unroll
    for (int i = 0; i < 4; ++i)
#pragma unroll
        for (int j = 0; j < 2; ++j) acc[i][j] = (f32x4){0.f, 0.f, 0.f, 0.f};

    const ushort_t* kfp = Kb + ((size_t)(b * SEQ) + ks * 1024 + w * 16 + ln) * DK;
    const ushort_t* vfp = VbT + ((size_t)(b * DK) + w * 32 + ln) * SEQ + ks * 1024 + quad * 8;

    bf16x8 kf0[4], kf1[4], vf0[4], vf1[4];

#define QK_PHASE(P, KF)                                                        \
    {                                                                          \
        _Pragma("unroll")                                                      \
        for (int nt = 0; nt < 4; ++nt) {                                       \
            f32x4 s = {0.f, 0.f, 0.f, 0.f};                                    \
            _Pragma("unroll")                                                  \
            for (int c = 0; c < 4; ++c)                                        \
                s = __builtin_amdgcn_mfma_f32_16x16x32_bf16(KF[c], qa[c][nt], s, 0, 0, 0); \
            uint2 pw;                                                          \
            pw.x = pk_bf16(__builtin_amdgcn_exp2f(C1_SCALE * s[0]),            \
                           __builtin_amdgcn_exp2f(C1_SCALE * s[1]));           \
            pw.y = pk_bf16(__builtin_amdgcn_exp2f(C1_SCALE * s[2]),            \
                           __builtin_amdgcn_exp2f(C1_SCALE * s[3]));           \
            const int q = nt * 16 + ln;                                        \
            const int a16 = w * 2 + (quad >> 1);                               \
            *(uint2*)&Pt[P][q * 64 + ((a16 ^ (q & 7)) * 8) + (quad & 1) * 4] = pw; \
        }                                                                      \
    }
#define PREFETCH(KF, VF, I1)                                                   \
    {                                                                          \
        _Pragma("unroll")                                                      \
        for (int c = 0; c < 4; ++c)                                            \
            KF[c] = *(const bf16x8*)(kfp + (size_t)(I1) * 64 * DK +            \
                                     (((c * 4 + quad) ^ ln) * 8));             \
        _Pragma("unroll")                                                      \
        for (int dt = 0; dt < 2; ++dt)                                         \
            _Pragma("unroll")                                                  \
            for (int kc = 0; kc < 2; ++kc)                                     \
                VF[kc * 2 + dt] = *(const bf16x8*)(vfp +                       \
                    (size_t)dt * 16 * SEQ + (size_t)(I1) * 64 + kc * 32);      \
    }
#define PV_PHASE(P, VF)                                                        \
    {                                                                          \
        _Pragma("unroll")                                                      \
        for (int kc = 0; kc < 2; ++kc) {                                       \
            bf16x8 pa[4];                                                      \
            _Pragma("unroll")                                                  \
            for (int qf2 = 0; qf2 < 4; ++qf2)                                  \
                pa[qf2] = *(const bf16x8*)&Pt[P][(qf2 * 16 + ln) * 64 +        \
                                    (((kc * 4 + quad) ^ (ln & 7)) * 8)];       \
            _Pragma("unroll")                                                  \
            for (int qf2 = 0; qf2 < 4; ++qf2)                                  \
                _Pragma("unroll")                                              \
                for (int dt = 0; dt < 2; ++dt)                                 \
                    acc[qf2][dt] = __builtin_amdgcn_mfma_f32_16x16x32_bf16(    \
                        pa[qf2], VF[kc * 2 + dt], acc[qf2][dt], 0, 0, 0);      \
        }                                                                      \
    }

#pragma unroll
    for (int c = 0; c < 4; ++c)
        kf0[c] = *(const bf16x8*)(kfp + (((c * 4 + quad) ^ ln) * 8));
#pragma unroll
    for (int dt = 0; dt < 2; ++dt)
#pragma unroll
        for (int kc = 0; kc < 2; ++kc)
            vf0[kc * 2 + dt] = *(const bf16x8*)(vfp + (size_t)dt * 16 * SEQ + kc * 32);

    for (int ii = 0; ii < 8; ++ii) {
        const int i0 = 2 * ii;
        PREFETCH(kf1, vf1, i0 + 1)
        QK_PHASE(0, kf0)
        __syncthreads();
        PV_PHASE(0, vf0)
        if (ii < 7) PREFETCH(kf0, vf0, i0 + 2)
        QK_PHASE(1, kf1)
        __syncthreads();
        PV_PHASE(1, vf1)
    }
#undef QK_PHASE
#undef PREFETCH
#undef PV_PHASE

#pragma unroll
    for (int qf2 = 0; qf2 < 4; ++qf2)
#pragma unroll
        for (int dt = 0; dt < 2; ++dt)
#pragma unroll
            for (int r = 0; r < 4; ++r)
                atomicAdd(&O[((size_t)(b * SEQ) + qt * 64 + qf2 * 16 + quad * 4 + r) * DK +
                             w * 32 + dt * 16 + ln], acc[qf2][dt][r]);
}

extern "C" void kernel_launch(void* const* d_in, const int* in_sizes, int n_in,
                              void* d_out, int out_size, void* d_ws, size_t ws_size,
                              hipStream_t stream) {
    const float* q = (const float*)d_in[0];
    const float* k = (const float*)d_in[1];
    const float* v = (const float*)d_in[2];
    float* out = (float*)d_out;

    const size_t QKV = (size_t)BS * SEQ * DK;           // 2 MB elements
    float*    lp  = (float*)d_ws;                       // 512 KB used
    ushort_t* Qb  = (ushort_t*)((char*)d_ws + (1 << 20));
    ushort_t* Kb  = Qb + QKV;
    ushort_t* VbT = Kb + QKV;
    ushort_t* Pg  = VbT + QKV;                          // 134 MB
    float*    Op  = (float*)(Pg + (size_t)BS * SEQ * SEQ);  // 33.6 MB

    const size_t need1 = (1u << 20) + 3 * QKV * 2 + (size_t)BS * SEQ * SEQ * 2;
    const size_t need2 = need1 + 4 * QKV * sizeof(float);

    cast_qk_sw<<<dim3(BS * SEQ * 16 / 256), 256, 0, stream>>>(q, k, Qb, Kb);

    if (ws_size >= need2) {
        sdpa_passA  <<<dim3(32, 8, 4), 256, 0, stream>>>(Qb, Kb, Pg, lp);
        vb_transpose<<<dim3(64, 4),    256, 0, stream>>>(v, lp, VbT);
        sdpa_passB  <<<dim3(16, 64),   256, 0, stream>>>(Pg, VbT, Op, out, 1);
        reduce4     <<<dim3(BS * SEQ * DK / 4 / 256), 256, 0, stream>>>(Op, out);
    } else if (ws_size >= need1) {
        hipMemsetAsync(out, 0, QKV * sizeof(float), stream);
        sdpa_passA  <<<dim3(32, 8, 4), 256, 0, stream>>>(Qb, Kb, Pg, lp);
        vb_transpose<<<dim3(64, 4),    256, 0, stream>>>(v, lp, VbT);
        sdpa_passB  <<<dim3(16, 64),   256, 0, stream>>>(Pg, VbT, (float*)Pg, out, 0);
    } else {
        hipMemsetAsync(out, 0, QKV * sizeof(float), stream);
        sdpa_lsum_fb<<<dim3(32, 8, 4), 256, 0, stream>>>(Qb, Kb, lp);
        vb_transpose<<<dim3(64, 4),    256, 0, stream>>>(v, lp, VbT);
        sdpa_out_fb <<<dim3(16, 64),   256, 0, stream>>>(Qb, Kb, VbT, out);
    }
}